// Round 15
// baseline (834.800 us; speedup 1.0000x reference)
//
#include <hip/hip_runtime.h>

#define NB 8
#define NN 2048
#define MM 2048
#define DD 64
#define NMAT ((size_t)NN * (size_t)MM)
#define NCHK 16
#define TS 128
#define NTILE 528          // 256 (Cxy) + 136 (Cxx tri) + 136 (Cyy tri)
#define TELEM 16384        // u16 elements per 128x128 tile

// uint16 fixed-point encoding of C (verified exact: rounds 5-14 absmax 0.0)
#define CSCALE 320.0f
#define CDEC   (1.0f / CSCALE)
#define LOG2E  1.4426950408889634f
#define LN2    0.6931471805599453f

typedef _Float16 half_t;
typedef __attribute__((ext_vector_type(8))) _Float16 f16x8;
typedef __attribute__((ext_vector_type(4))) float f32x4;

// ---------------------------------------------------------------------------
// Static device scratch. C stored TILE-CONTIGUOUS in MFMA fragment-native
// order: tile blob = 32 KB; uint4 #(k*256 + t) holds thread t's cols
// {16c + m} (c=0..7 packed) of row 32w+16g+4quad+r, k = g*4+r.
// Layout: [b][tile] where tile = xid (0..255 Cxy, 256..391 Cxx, 392..527 Cyy).
// ---------------------------------------------------------------------------
__device__ unsigned short g_C[(size_t)NB * NTILE * TELEM];   // 138 MB
__device__ half_t g_xh[NB * NN * DD];           // fp16 copies for MFMA
__device__ half_t g_yh[NB * MM * DD];
// potential banks: [0]/[1] = carry double-buffer, [2] = final
__device__ float g_fab[3][NB * NN], g_gba[3][NB * NN];
__device__ float g_faa[3][NB * NN], g_gbb[3][NB * NN];
__device__ float g_alog[NB * NN], g_blog[NB * NN];
__device__ float g_xn[NB * NN], g_yn[NB * NN];
__device__ float g_h0[NB * MM], g_h1[NB * NN], g_h2[NB * NN], g_h3[NB * MM];
// chunked softmin partials (m2, s): m2 in BASE-2 log units
__device__ float2 g_pfab[NB * NCHK * NN];
__device__ float2 g_pgba[NB * NCHK * NN];
__device__ float2 g_pfaa[NB * NCHK * NN];
__device__ float2 g_pgbb[NB * NCHK * NN];

// decode flat tile id -> slab (0/1/2) and (I,J); sym slabs use tri order
__device__ __forceinline__ void tile_decode(int xid, int& slab, int& I, int& J)
{
  int tid;
  if (xid < 256)      { slab = 0; tid = xid; I = tid >> 4; J = tid & 15; return; }
  else if (xid < 392) { slab = 1; tid = xid - 256; }
  else                { slab = 2; tid = xid - 392; }
  int rem = tid, ii = 0;
  while (rem >= NCHK - ii) { rem -= NCHK - ii; ++ii; }   // uniform, <=16 iters
  I = ii; J = ii + rem;                                  // I <= J
}

// ---------------------------------------------------------------------------
// prep: a_log/b_log = log(w), xn/yn = 0.5*||row||^2, and fp16 copies of x,y.
// ---------------------------------------------------------------------------
__global__ __launch_bounds__(256) void prep_kernel(
    const float* __restrict__ x, const float* __restrict__ y,
    const float* __restrict__ w1, const float* __restrict__ w2)
{
  int gid = blockIdx.x * 256 + threadIdx.x;
  if (gid < NB * NN) {
    g_alog[gid] = logf(w1[gid]);
    g_blog[gid] = logf(w2[gid]);
  }
  int lane = threadIdx.x & 63;
  int row = blockIdx.x * 4 + (threadIdx.x >> 6);   // grid 4096 -> rows 0..16383
  float xv = x[(size_t)row * DD + lane];
  float yv = y[(size_t)row * DD + lane];
  g_xh[(size_t)row * DD + lane] = (half_t)xv;
  g_yh[(size_t)row * DD + lane] = (half_t)yv;
  float sx = xv * xv;
  float sy = yv * yv;
#pragma unroll
  for (int off = 32; off > 0; off >>= 1) {
    sx += __shfl_down(sx, off);
    sy += __shfl_down(sy, off);
  }
  if (lane == 0) {
    g_xn[row] = 0.5f * sx;
    g_yn[row] = 0.5f * sy;
  }
}

// ---------------------------------------------------------------------------
// MFMA cost build, fragment-native epilogue: NO LDS, NO barrier — 8 coalesced
// uint4 stores per thread into the tile blob. MFMA body verified r9-r14.
// grid (528, 8).
// ---------------------------------------------------------------------------
__global__ __launch_bounds__(256) void cost_mfma()
{
  int slab, I, J;
  tile_decode(blockIdx.x, slab, I, J);
  const int b = blockIdx.y;

  const half_t* Ah = (slab == 2) ? g_yh : g_xh;
  const half_t* Bh = (slab == 0) ? g_yh : ((slab == 1) ? g_xh : g_yh);
  const float* na = (slab == 2) ? g_yn : g_xn;
  const float* nbp = (slab == 0) ? g_yn : ((slab == 1) ? g_xn : g_yn);

  const int t = threadIdx.x;
  const int w = t >> 6, lane = t & 63;
  const int m = lane & 15, quad = lane >> 4;
  const int i0 = I * TS, j0 = J * TS;

  const half_t* Abase = Ah + ((size_t)b * NN + i0 + 32 * w + m) * DD + quad * 8;
  const half_t* Bbase = Bh + ((size_t)b * MM + j0 + m) * DD + quad * 8;

  f32x4 acc[2][8];
#pragma unroll
  for (int g = 0; g < 2; ++g)
#pragma unroll
    for (int c = 0; c < 8; ++c) acc[g][c] = (f32x4){0.f, 0.f, 0.f, 0.f};

#pragma unroll
  for (int s = 0; s < 2; ++s) {
    f16x8 a0 = *(const f16x8*)(Abase + s * 32);
    f16x8 a1 = *(const f16x8*)(Abase + (size_t)16 * DD + s * 32);
#pragma unroll
    for (int c = 0; c < 8; ++c) {
      f16x8 bf = *(const f16x8*)(Bbase + (size_t)(16 * c) * DD + s * 32);
      acc[0][c] = __builtin_amdgcn_mfma_f32_16x16x32_f16(a0, bf, acc[0][c], 0, 0, 0);
      acc[1][c] = __builtin_amdgcn_mfma_f32_16x16x32_f16(a1, bf, acc[1][c], 0, 0, 0);
    }
  }

  float4 xr[2];
#pragma unroll
  for (int g = 0; g < 2; ++g)
    xr[g] = *(const float4*)(na + b * NN + i0 + 32 * w + 16 * g + 4 * quad);
  float yv[8];
#pragma unroll
  for (int c = 0; c < 8; ++c) yv[c] = nbp[b * MM + j0 + 16 * c + m];

  uint4* Cout = (uint4*)(g_C + ((size_t)b * NTILE + blockIdx.x) * TELEM);
#pragma unroll
  for (int k = 0; k < 8; ++k) {
    int g = k >> 2, r = k & 3;
    float xg = (r == 0) ? xr[g].x : (r == 1) ? xr[g].y : (r == 2) ? xr[g].z : xr[g].w;
    unsigned int u[8];
#pragma unroll
    for (int c = 0; c < 8; ++c) {
      float cv = fmaxf(xg + yv[c] - acc[g][c][r], 0.f);
      u[c] = __float2uint_rn(fminf(cv * CSCALE, 65535.f));
    }
    uint4 ow;
    ow.x = u[0] | (u[1] << 16);
    ow.y = u[2] | (u[3] << 16);
    ow.z = u[4] | (u[5] << 16);
    ow.w = u[6] | (u[7] << 16);
    Cout[k * 256 + t] = ow;   // fully coalesced, tile-contiguous
  }
}

// ---------------------------------------------------------------------------
// h-vector prep — used ONCE for the init step (gs = 0); subsequent h's are
// written by merge4. h stays in NATURAL log units.
// ---------------------------------------------------------------------------
__global__ __launch_bounds__(256) void hprep_kernel(
    const float* __restrict__ fab_in, const float* __restrict__ gba_in,
    const float* __restrict__ faa_in, const float* __restrict__ gbb_in,
    float gs)
{
  int i = blockIdx.x * 256 + threadIdx.x;   // grid 64 -> 16384
  g_h0[i] = fmaf(gs, gba_in[i], g_blog[i]);
  g_h1[i] = fmaf(gs, fab_in[i], g_alog[i]);
  g_h2[i] = fmaf(gs, faa_in[i], g_alog[i]);
  g_h3[i] = fmaf(gs, gbb_in[i], g_blog[i]);
}

// ---------------------------------------------------------------------------
// Tile-partial softmin pass on fragment-native tiles. 8 coalesced uint4
// loads stream one contiguous 32 KB blob. Two-phase max/sum (base-2 domain):
//  - row-dir (reduce over cols): in-thread over c, butterfly over m (bits 0-3)
//  - col-dir (reduce over rows): in-thread over k=(g,r), butterfly over quad
//    (bits 4-5), 4-way LDS merge over waves.
// Partials (m2, s) identical in meaning to r14's — merge4 unchanged.
// grid (528, 8).
// ---------------------------------------------------------------------------
struct TileArgs {
  const float* hrow;
  const float* hcol;
  float2* prow;   // [b][chunk][row]
  float2* pcol;
  int sym;
};

__global__ __launch_bounds__(256) void tile_pass(
    TileArgs T0, TileArgs T1, TileArgs T2, float inv_eps)
{
  int slab, I, J;
  tile_decode(blockIdx.x, slab, I, J);
  TileArgs A = (slab == 0) ? T0 : (slab == 1) ? T1 : T2;
  const int b = blockIdx.y;
  const int t = threadIdx.x;
  const int w = t >> 6, lane = t & 63;
  const int m = lane & 15, quad = lane >> 4;
  const float cs2 = -inv_eps * CDEC * LOG2E;

  const uint4* Cb = (const uint4*)(g_C + ((size_t)b * NTILE + blockIdx.x) * TELEM);
  uint4 cu[8];
#pragma unroll
  for (int k = 0; k < 8; ++k) cu[k] = Cb[k * 256 + t];

  // row-dir weights: cols j = J*TS + 16c + m
  float hr2[8];
#pragma unroll
  for (int c = 0; c < 8; ++c)
    hr2[c] = A.hrow[b * MM + J * TS + 16 * c + m] * LOG2E;
  // col-dir weights: rows i = I*TS + 32w + 16g + 4quad + r  (k = g*4+r)
  float hc2[8];
#pragma unroll
  for (int g = 0; g < 2; ++g) {
    float4 h4 = *(const float4*)(A.hcol + b * NN + I * TS + 32 * w + 16 * g + 4 * quad);
    hc2[g * 4 + 0] = h4.x * LOG2E;
    hc2[g * 4 + 1] = h4.y * LOG2E;
    hc2[g * 4 + 2] = h4.z * LOG2E;
    hc2[g * 4 + 3] = h4.w * LOG2E;
  }

  __shared__ float redC[TS][5];   // [col][wave], 5 stride kills conflicts
  __shared__ float colM[TS];

  // ---- phase A: maxes ----
  float rm[8], cm[8];
#pragma unroll
  for (int k = 0; k < 8; ++k) { rm[k] = -3.0e38f; cm[k] = -3.0e38f; }
#pragma unroll
  for (int k = 0; k < 8; ++k) {
    float u[8];
    u[0] = (float)(cu[k].x & 0xffff);
    u[1] = (float)(cu[k].x >> 16);
    u[2] = (float)(cu[k].y & 0xffff);
    u[3] = (float)(cu[k].y >> 16);
    u[4] = (float)(cu[k].z & 0xffff);
    u[5] = (float)(cu[k].z >> 16);
    u[6] = (float)(cu[k].w & 0xffff);
    u[7] = (float)(cu[k].w >> 16);
#pragma unroll
    for (int c = 0; c < 8; ++c) {
      rm[k] = fmaxf(rm[k], fmaf(u[c], cs2, hr2[c]));
      cm[c] = fmaxf(cm[c], fmaf(u[c], cs2, hc2[k]));
    }
  }
  // row maxes: butterfly over m (lane bits 0-3)
#pragma unroll
  for (int mask = 1; mask < 16; mask <<= 1)
#pragma unroll
    for (int k = 0; k < 8; ++k)
      rm[k] = fmaxf(rm[k], __shfl_xor(rm[k], mask));
  // col maxes: butterfly over quad (bits 4-5), then LDS over the 4 waves
#pragma unroll
  for (int mask = 16; mask < 64; mask <<= 1)
#pragma unroll
    for (int c = 0; c < 8; ++c)
      cm[c] = fmaxf(cm[c], __shfl_xor(cm[c], mask));
  if (quad == 0) {
#pragma unroll
    for (int c = 0; c < 8; ++c) redC[16 * c + m][w] = cm[c];
  }
  __syncthreads();
  if (t < TS) {
    float v = fmaxf(fmaxf(redC[t][0], redC[t][1]),
                    fmaxf(redC[t][2], redC[t][3]));
    colM[t] = v;
  }
  __syncthreads();
  float cmv[8];
#pragma unroll
  for (int c = 0; c < 8; ++c) cmv[c] = colM[16 * c + m];

  // ---- phase B: sums (recompute v from registers; bare v_exp_f32) ----
  float rs[8], cs[8];
#pragma unroll
  for (int k = 0; k < 8; ++k) { rs[k] = 0.f; cs[k] = 0.f; }
#pragma unroll
  for (int k = 0; k < 8; ++k) {
    float u[8];
    u[0] = (float)(cu[k].x & 0xffff);
    u[1] = (float)(cu[k].x >> 16);
    u[2] = (float)(cu[k].y & 0xffff);
    u[3] = (float)(cu[k].y >> 16);
    u[4] = (float)(cu[k].z & 0xffff);
    u[5] = (float)(cu[k].z >> 16);
    u[6] = (float)(cu[k].w & 0xffff);
    u[7] = (float)(cu[k].w >> 16);
#pragma unroll
    for (int c = 0; c < 8; ++c) {
      rs[k] += __builtin_amdgcn_exp2f(fmaf(u[c], cs2, hr2[c]) - rm[k]);
      cs[c] += __builtin_amdgcn_exp2f(fmaf(u[c], cs2, hc2[k]) - cmv[c]);
    }
  }
  // row sums: butterfly over m; lanes m<8 write k=m
#pragma unroll
  for (int mask = 1; mask < 16; mask <<= 1)
#pragma unroll
    for (int k = 0; k < 8; ++k)
      rs[k] += __shfl_xor(rs[k], mask);
  if (m < 8) {
    int k = m;
    int i = I * TS + 32 * w + 16 * (k >> 2) + 4 * quad + (k & 3);
    A.prow[((size_t)b * NCHK + J) * NN + i] = make_float2(rm[k], rs[k]);
  }
  // col sums: butterfly over quad, LDS over waves
#pragma unroll
  for (int mask = 16; mask < 64; mask <<= 1)
#pragma unroll
    for (int c = 0; c < 8; ++c)
      cs[c] += __shfl_xor(cs[c], mask);
  __syncthreads();   // safe to reuse redC
  if (quad == 0) {
#pragma unroll
    for (int c = 0; c < 8; ++c) redC[16 * c + m][w] = cs[c];
  }
  __syncthreads();
  if (t < TS && !(A.sym && I == J)) {   // diagonal col-dir duplicates row-dir
    float s = redC[t][0] + redC[t][1] + redC[t][2] + redC[t][3];
    A.pcol[((size_t)b * NCHK + I) * NN + J * TS + t] = make_float2(colM[t], s);
  }
}

// ---------------------------------------------------------------------------
// merge 16 chunk-partials per row (BASE-2 partials) -> softmin + Jacobi
// update + next-h write. (verified r14)
// ---------------------------------------------------------------------------
struct MergeArgs {
  const float2* part;
  const float* fold;
  float* fout;
  const float* hbase;   // alog or blog
  float* hout;          // h vector consumed by the next tile_pass
};

__global__ __launch_bounds__(256) void merge4(
    MergeArgs M0, MergeArgs M1, MergeArgs M2, MergeArgs M3,
    float eps, float alpha, float beta, float nextgs)
{
  MergeArgs A = (blockIdx.z == 0) ? M0 : (blockIdx.z == 1) ? M1
              : (blockIdx.z == 2) ? M2 : M3;
  const int b = blockIdx.y;
  const int i = blockIdx.x * 256 + threadIdx.x;   // grid.x = NN/256
  float2 p[NCHK];
#pragma unroll
  for (int k = 0; k < NCHK; ++k)
    p[k] = A.part[((size_t)b * NCHK + k) * NN + i];
  float M = p[0].x;
#pragma unroll
  for (int k = 1; k < NCHK; ++k) M = fmaxf(M, p[k].x);
  float S = 0.f;
#pragma unroll
  for (int k = 0; k < NCHK; ++k)
    S += p[k].y * __builtin_amdgcn_exp2f(p[k].x - M);
  float ft = -eps * LN2 * (M + __builtin_amdgcn_logf(S));
  int idx = b * NN + i;
  float fnew = alpha * A.fold[idx] + beta * ft;
  A.fout[idx] = fnew;
  A.hout[idx] = fmaf(nextgs, fnew, A.hbase[idx]);
}

// ---------------------------------------------------------------------------
// loss = mean_b [ sum_i w1*(fabf - faaf) + sum_j w2*(gbaf - gbbf) ]
// ---------------------------------------------------------------------------
__global__ __launch_bounds__(256) void loss_kernel(
    const float* __restrict__ w1, const float* __restrict__ w2,
    float* __restrict__ out)
{
  __shared__ float red[256];
  float acc = 0.f;
  for (int idx = threadIdx.x; idx < NB * NN; idx += 256) {
    acc += w1[idx] * (g_fab[2][idx] - g_faa[2][idx])
         + w2[idx] * (g_gba[2][idx] - g_gbb[2][idx]);
  }
  red[threadIdx.x] = acc;
  __syncthreads();
  for (int s = 128; s > 0; s >>= 1) {
    if (threadIdx.x < s) red[threadIdx.x] += red[threadIdx.x + s];
    __syncthreads();
  }
  if (threadIdx.x == 0) out[0] = red[0] * (1.0f / NB);
}

// ---------------------------------------------------------------------------
extern "C" void kernel_launch(void* const* d_in, const int* in_sizes, int n_in,
                              void* d_out, int out_size, void* d_ws, size_t ws_size,
                              hipStream_t stream)
{
  const float* x = (const float*)d_in[0];
  const float* y = (const float*)d_in[1];
  const float* w1 = (const float*)d_in[2];
  const float* w2 = (const float*)d_in[3];
  float* out = (float*)d_out;

  float *h0, *h1, *h2, *h3, *fabp, *gbap, *faap, *gbbp, *alog, *blog;
  float2 *pfab, *pgba, *pfaa, *pgbb;
  hipGetSymbolAddress((void**)&h0, HIP_SYMBOL(g_h0));
  hipGetSymbolAddress((void**)&h1, HIP_SYMBOL(g_h1));
  hipGetSymbolAddress((void**)&h2, HIP_SYMBOL(g_h2));
  hipGetSymbolAddress((void**)&h3, HIP_SYMBOL(g_h3));
  hipGetSymbolAddress((void**)&fabp, HIP_SYMBOL(g_fab));
  hipGetSymbolAddress((void**)&gbap, HIP_SYMBOL(g_gba));
  hipGetSymbolAddress((void**)&faap, HIP_SYMBOL(g_faa));
  hipGetSymbolAddress((void**)&gbbp, HIP_SYMBOL(g_gbb));
  hipGetSymbolAddress((void**)&alog, HIP_SYMBOL(g_alog));
  hipGetSymbolAddress((void**)&blog, HIP_SYMBOL(g_blog));
  hipGetSymbolAddress((void**)&pfab, HIP_SYMBOL(g_pfab));
  hipGetSymbolAddress((void**)&pgba, HIP_SYMBOL(g_pgba));
  hipGetSymbolAddress((void**)&pfaa, HIP_SYMBOL(g_pfaa));
  hipGetSymbolAddress((void**)&pgbb, HIP_SYMBOL(g_pgbb));

  auto fab = [&](int s) { return fabp + (size_t)s * NB * NN; };
  auto gba = [&](int s) { return gbap + (size_t)s * NB * NN; };
  auto faa = [&](int s) { return faap + (size_t)s * NB * NN; };
  auto gbb = [&](int s) { return gbbp + (size_t)s * NB * NN; };

  // eps schedule (matches the Python double loop, then cast to fp32)
  float eps_list[32];
  int ne = 0;
  {
    double v = 64.0 * 64.0;
    double tgt = 0.05 * 0.05;
    while (v > tgt) { eps_list[ne++] = (float)v; v *= 0.25; }
    eps_list[ne++] = (float)tgt;   // ne == 12
  }

  prep_kernel<<<4096, 256, 0, stream>>>(x, y, w1, w2);

  // all three cost slabs, flat 528-tile grid, fragment-native output
  cost_mfma<<<dim3(NTILE, NB), 256, 0, stream>>>();

  dim3 tg(NTILE, NB);           // flat: 0..255 Cxy, 256..391 Cxx, 392..527 Cyy
  dim3 mg(NN / 256, NB, 4);     // z: potential

  // one iteration: tile_pass (h already in place) + merge4 (writes next h)
  auto launch_iter = [&](float eps, float alpha, float beta, float nextgs,
                         int in, int outsel) {
    float inv = 1.0f / eps;
    TileArgs T0 = {h0, h1, pfab, pgba, 0};
    TileArgs T1 = {h2, h2, pfaa, pfaa, 1};
    TileArgs T2 = {h3, h3, pgbb, pgbb, 1};
    tile_pass<<<tg, 256, 0, stream>>>(T0, T1, T2, inv);
    MergeArgs M0 = {pfab, fab(in), fab(outsel), alog, h1};
    MergeArgs M1 = {pgba, gba(in), gba(outsel), blog, h0};
    MergeArgs M2 = {pfaa, faa(in), faa(outsel), alog, h2};
    MergeArgs M3 = {pgbb, gbb(in), gbb(outsel), blog, h3};
    merge4<<<mg, 256, 0, stream>>>(M0, M1, M2, M3, eps, alpha, beta, nextgs);
  };

  // init at eps0: h = base log-weights (gs=0), alpha=0 -> no carry read;
  // its merge writes h for scan step k=0.
  hprep_kernel<<<64, 256, 0, stream>>>(fab(0), gba(0), faa(0), gbb(0), 0.f);
  launch_iter(eps_list[0], 0.f, 1.f, 1.0f / eps_list[0], 0, 0);

  // scan over the full eps list with 0.5-averaging (Jacobi, banks 0/1);
  // each merge writes h for the NEXT step (k+1, or the final extrapolation).
  int cur = 0;
  for (int k = 0; k < ne; ++k) {
    int nxt = 1 - cur;
    float nextgs = 1.0f / ((k < ne - 1) ? eps_list[k + 1] : eps_list[ne - 1]);
    launch_iter(eps_list[k], 0.5f, 0.5f, nextgs, cur, nxt);
    cur = nxt;
  }

  // final extrapolation at eps = blur^p (no averaging) -> bank 2
  launch_iter(eps_list[ne - 1], 0.f, 1.f, 0.f, cur, 2);

  loss_kernel<<<1, 256, 0, stream>>>(w1, w2, out);
}